// Round 15
// baseline (255.759 us; speedup 1.0000x reference)
//
#include <hip/hip_runtime.h>
#include <hip/hip_bf16.h>

// SpatialCrossAttention (BEVFormer SCA) fused pipeline for MI355X/gfx950.
//  K0 detect  : infer bev_mask storage layout (u8 / i32 / f32)
//  K1 hit     : hit[c][q], invcnt[q]
//  K2 prep    : bf16 W-fragment tables for the 3 GEMMs (+ concat bias)
//  gemm_v     : operand-swapped MFMA GEMM, W-table quarter-staged in 2x32KB LDS.
//               v3: 1024 thr / 16 waves, wave = 32 rows x 64 cols -> each W-frag
//               ds_read feeds TWO MFMAs (LDS reads halved vs R14) with block
//               staging traffic unchanged. Plain 4B stores (R11-verified clean).
//  gemm_oa/out: small GEMMs, quarter-staged LDS body.
//  K4 sample  : fused softmax + bilinear gather (HW fp8 cvt) + cam-average
//               (natural layout, measured 101us).

__device__ __forceinline__ void gload_lds16(const void* g, void* l) {
    __builtin_amdgcn_global_load_lds(
        (const __attribute__((address_space(1))) unsigned*)g,
        (__attribute__((address_space(3))) unsigned*)l, 16, 0, 0);
}

typedef __attribute__((ext_vector_type(8))) short short8;
typedef __attribute__((ext_vector_type(4))) float f32x4;
typedef __attribute__((ext_vector_type(2))) float floatx2;

__device__ __forceinline__ short f2bf(float f) {
    union { float f; unsigned u; } c; c.f = f;
    unsigned u = c.u;
    unsigned r = (u + 0x7FFFu + ((u >> 16) & 1u)) >> 16;  // RNE
    return (short)r;
}

// ---- fp8 e4m3fn decode/encode: HW cvt on gfx950, manual fallback ----
__device__ __forceinline__ float e4m3f_manual(unsigned b) {
    unsigned s = (b & 0x80u) << 24;
    unsigned e = (b >> 3) & 15u;
    unsigned m = b & 7u;
    if (e) return __uint_as_float(s | ((e + 120u) << 23) | (m << 20));
    return __uint_as_float(s | __float_as_uint((float)m * 0x1p-9f));
}
__device__ __forceinline__ unsigned char f2e4m3_manual(float x) {
    unsigned u = __float_as_uint(x);
    unsigned s = (u >> 24) & 0x80u;
    float ax = fabsf(x);
    if (!(ax > 0x1p-10f)) return (unsigned char)s;
    if (ax >= 440.f) return (unsigned char)(s | 0x7Eu);
    unsigned au = u & 0x7FFFFFFFu;
    int e = (int)(au >> 23) - 127;
    if (e >= -6) {
        unsigned r = au + 0x7FFFFu + ((au >> 20) & 1u);
        e = (int)(r >> 23) - 127;
        unsigned m = (r >> 20) & 7u;
        if (e > 8) return (unsigned char)(s | 0x7Eu);
        return (unsigned char)(s | (unsigned)((e + 7) << 3) | m);
    } else {
        int m = (int)rintf(ax * 512.f);
        return (unsigned char)(s | (unsigned)m);
    }
}

static constexpr int QN   = 10000;
static constexpr int CAMS = 6;
static constexpr int NV   = 23200;   // 116*200
static constexpr int HH   = 116;
static constexpr int WW   = 200;
static constexpr int MROW = CAMS * NV;  // 139200

// ---------------- K0: mask layout detect (16KB scan) ----------------
__global__ void detect_kernel(const unsigned char* __restrict__ mask, int* __restrict__ flag) {
    __shared__ unsigned s12[256], s3[256];
    unsigned o12 = 0, o3 = 0;
    for (int i = threadIdx.x; i < 16384; i += 256) {
        unsigned char b = mask[i];
        int m = i & 3;
        if (m == 1 || m == 2) o12 |= b;
        else if (m == 3) o3 |= b;
    }
    s12[threadIdx.x] = o12; s3[threadIdx.x] = o3;
    __syncthreads();
    if (threadIdx.x == 0) {
        unsigned a = 0, b = 0;
        for (int i = 0; i < 256; i++) { a |= s12[i]; b |= s3[i]; }
        *flag = a ? 0 : (b ? 2 : 1);  // 0=u8, 1=i32, 2=f32
    }
}

// ---------------- K1: hit / invcount ----------------
__global__ void hit_kernel(const void* __restrict__ mask, const int* __restrict__ flag,
                           float* __restrict__ hit, float* __restrict__ invcnt) {
    int q = blockIdx.x * 256 + threadIdx.x;
    if (q >= QN) return;
    int f = *flag;
    int cnt = 0;
    for (int c = 0; c < CAMS; c++) {
        bool any = false;
        #pragma unroll
        for (int d = 0; d < 4; d++) {
            size_t i = (size_t)(c * QN + q) * 4 + d;
            bool b;
            if (f == 0)      b = ((const unsigned char*)mask)[i] != 0;
            else if (f == 1) b = ((const int*)mask)[i] != 0;
            else             b = ((const float*)mask)[i] != 0.f;
            any |= b;
        }
        hit[c * QN + q] = any ? 1.f : 0.f;
        cnt += any ? 1 : 0;
    }
    invcnt[q] = 1.f / (float)(cnt > 0 ? cnt : 1);
}

// ---------------- K2: weight fragment tables ----------------
// entry e = ((kc*16 + nt)*64 + lane)*8 + j ;  W[kc*32 + (lane>>4)*8 + j][nt*16 + (lane&15)]
__global__ void prep_kernel(const float* __restrict__ wv, const float* __restrict__ woff,
                            const float* __restrict__ wattn, const float* __restrict__ wout,
                            const float* __restrict__ boff, const float* __restrict__ battn,
                            short* __restrict__ tv, short* __restrict__ toa,
                            short* __restrict__ tout, float* __restrict__ biasOA) {
    int id = blockIdx.x * 256 + threadIdx.x;
    if (id < 3 * 65536) {
        int t = id >> 16;
        int e = id & 65535;
        int j = e & 7, l = (e >> 3) & 63, nt = (e >> 9) & 15, kc = e >> 13;
        int k = kc * 32 + ((l >> 4) << 3) + j;
        int col = nt * 16 + (l & 15);
        float v;
        if (t == 0)      v = wv[k * 256 + col];
        else if (t == 1) v = (col < 128) ? woff[k * 128 + col]
                               : (col < 192 ? wattn[k * 64 + (col - 128)] : 0.f);
        else             v = wout[k * 256 + col];
        short* dst = (t == 0) ? tv : (t == 1) ? toa : tout;
        dst[e] = f2bf(v);
    } else {
        int i = id - 3 * 65536;
        if (i < 192) biasOA[i] = (i < 128) ? boff[i] : battn[i - 128];
    }
}

__device__ __forceinline__ short8 cvt8(float4 x0, float4 x1) {
    unsigned u0, u1, u2, u3;
    asm("v_cvt_pk_bf16_f32 %0, %1, %2" : "=v"(u0) : "v"(x0.x), "v"(x0.y));
    asm("v_cvt_pk_bf16_f32 %0, %1, %2" : "=v"(u1) : "v"(x0.z), "v"(x0.w));
    asm("v_cvt_pk_bf16_f32 %0, %1, %2" : "=v"(u2) : "v"(x1.x), "v"(x1.y));
    asm("v_cvt_pk_bf16_f32 %0, %1, %2" : "=v"(u3) : "v"(x1.z), "v"(x1.w));
    union { unsigned u[4]; short8 s8; } uu;
    uu.u[0] = u0; uu.u[1] = u1; uu.u[2] = u2; uu.u[3] = u3;
    return uu.s8;
}

// ---------------- gemm_v v3: 16 waves, W-frag reuse, quarter-staged table -------
// out[m][n] = sum_k A[m][k]*W[k][n] + bias -> fp8 (natural layout).
// Block = 128 rows x 256 cols, 1024 thr / 16 waves.
// wave wv: wm=wv>>2 -> 32-row stripe; wn=wv&3 -> 4 nt (64 cols).
// Wave = 32 rows x 64 cols: acc[2][4] (32 VGPR); each W-frag ds_read feeds
// 2 MFMAs (rows lr and lr+16) -> ds_read_b128 per MFMA = 0.5.
// W table: 128KB = 4 quarters (2 kc) double-buffered in 2x32KB LDS, 4 barriers.
__global__ __launch_bounds__(1024)
void gemm_v(const float* __restrict__ A, const short* __restrict__ Wtab,
            const float* __restrict__ bias, void* __restrict__ out, int M) {
    __shared__ short tab[2][16384];                 // 2 x 32KB
    const int tid = threadIdx.x;
    const int l  = tid & 63;
    const int wv = tid >> 6;                        // 0..15
    const int wm = wv >> 2;                         // 0..3  (32-row stripe)
    const int wn = wv & 3;                          // 0..3  (4 nt)
    const int lr = l & 15;
    const int lg = l >> 4;
    const int rowBase = blockIdx.x * 128;

    const int mRow0 = rowBase + wm * 32 + lr;
    const int mRow1 = mRow0 + 16;
    const int m0 = min(mRow0, M - 1);
    const int m1 = min(mRow1, M - 1);
    const float* arow0 = A + (size_t)m0 * 256 + lg * 8;
    const float* arow1 = A + (size_t)m1 * 256 + lg * 8;

    auto load_q = [&](int b, int q) {
        #pragma unroll
        for (int it = 0; it < 2; it++) {
            int linear = (it * 1024 + tid) * 16;    // byte 0..32767
            const char* src = (const char*)Wtab + q * 32768 + linear;
            char* dst = (char*)&tab[b][0] + it * 16384 + (tid & 960) * 16;  // wave-uniform
            gload_lds16(src, dst);
        }
    };

    f32x4 acc[2][4] = {};

    auto step = [&](int b, int kk, float4 a0, float4 a1, float4 a2, float4 a3) {
        short8 bf0 = cvt8(a0, a1);
        short8 bf1 = cvt8(a2, a3);
        #pragma unroll
        for (int i = 0; i < 4; i++) {
            int nt = wn * 4 + i;
            short8 wf = *(const short8*)(&tab[b][(kk * 16 + nt) * 512 + l * 8]);
            acc[0][i] = __builtin_amdgcn_mfma_f32_16x16x32_bf16(wf, bf0, acc[0][i], 0, 0, 0);
            acc[1][i] = __builtin_amdgcn_mfma_f32_16x16x32_bf16(wf, bf1, acc[1][i], 0, 0, 0);
        }
    };

    float4 c0, c1, c2, c3, n0, n1, n2, n3;
    auto loadA = [&](int kc, float4& x0, float4& x1, float4& x2, float4& x3) {
        const float4* p0 = (const float4*)(arow0 + kc * 32);
        const float4* p1 = (const float4*)(arow1 + kc * 32);
        x0 = p0[0]; x1 = p0[1]; x2 = p1[0]; x3 = p1[1];
    };

    loadA(0, c0, c1, c2, c3);
    load_q(0, 0);
    __syncthreads();                  // q0 visible
    load_q(1, 1);

    loadA(1, n0, n1, n2, n3);  step(0, 0, c0, c1, c2, c3);   // kc0
    loadA(2, c0, c1, c2, c3);  step(0, 1, n0, n1, n2, n3);   // kc1
    __syncthreads();                  // q1 visible, buf0 free
    load_q(0, 2);
    loadA(3, n0, n1, n2, n3);  step(1, 0, c0, c1, c2, c3);   // kc2
    loadA(4, c0, c1, c2, c3);  step(1, 1, n0, n1, n2, n3);   // kc3
    __syncthreads();                  // q2 visible, buf1 free
    load_q(1, 3);
    loadA(5, n0, n1, n2, n3);  step(0, 0, c0, c1, c2, c3);   // kc4
    loadA(6, c0, c1, c2, c3);  step(0, 1, n0, n1, n2, n3);   // kc5
    __syncthreads();                  // q3 visible
    loadA(7, n0, n1, n2, n3);  step(1, 0, c0, c1, c2, c3);   // kc6
                               step(1, 1, n0, n1, n2, n3);   // kc7

    #pragma unroll
    for (int mg = 0; mg < 2; mg++) {
        int mRow = (mg == 0) ? mRow0 : mRow1;
        if (mRow >= M) continue;
        #pragma unroll
        for (int i = 0; i < 4; i++) {
            int nt = wn * 4 + i;
            int n0c = nt * 16 + lg * 4;
            float4 bv = *(const float4*)(bias + n0c);
            float v0 = acc[mg][i][0] + bv.x, v1 = acc[mg][i][1] + bv.y;
            float v2 = acc[mg][i][2] + bv.z, v3 = acc[mg][i][3] + bv.w;
            unsigned pk;
#if __has_builtin(__builtin_amdgcn_cvt_pk_fp8_f32)
            pk = __builtin_amdgcn_cvt_pk_fp8_f32(v0, v1, 0, false);
            pk = __builtin_amdgcn_cvt_pk_fp8_f32(v2, v3, pk, true);
#else
            pk = (unsigned)f2e4m3_manual(v0) | ((unsigned)f2e4m3_manual(v1) << 8)
               | ((unsigned)f2e4m3_manual(v2) << 16) | ((unsigned)f2e4m3_manual(v3) << 24);
#endif
            ((unsigned*)out)[(size_t)mRow * 64 + (n0c >> 2)] = pk;
        }
    }
}

// ---------------- small-GEMM body: W-table quarters in LDS ----------------
template <int MODE>
__device__ __forceinline__
void gemm_tab_body(const float* __restrict__ A, const short* __restrict__ Wtab,
                   const float* __restrict__ bias, const float* __restrict__ resid,
                   void* __restrict__ out, int M) {
    __shared__ short tab[2][16384];                 // 2 x 32KB
    const int tid = threadIdx.x;
    const int l  = tid & 63;
    const int wv = tid >> 6;
    const int wm = wv >> 2;
    const int wn = wv & 3;
    const int lr = l & 15;
    const int lg = l >> 4;
    const int rowBase = blockIdx.x * 64;

    const int mRow0 = rowBase + wm * 32 + lr;
    const int mRow1 = mRow0 + 16;
    const int m0 = min(mRow0, M - 1);
    const int m1 = min(mRow1, M - 1);
    const float* arow0 = A + (size_t)m0 * 256 + lg * 8;
    const float* arow1 = A + (size_t)m1 * 256 + lg * 8;

    auto load_q = [&](int b, int q) {
        #pragma unroll
        for (int it = 0; it < 4; it++) {
            int linear = (it * 512 + tid) * 16;
            const char* src = (const char*)Wtab + q * 32768 + linear;
            char* dst = (char*)&tab[b][0] + it * 8192 + (tid & 448) * 16;
            gload_lds16(src, dst);
        }
    };

    f32x4 acc[2][4] = {};

    auto step = [&](int b, int kk, float4 a0, float4 a1, float4 a2, float4 a3) {
        short8 bf0 = cvt8(a0, a1);
        short8 bf1 = cvt8(a2, a3);
        #pragma unroll
        for (int i = 0; i < 4; i++) {
            int nt = wn * 4 + i;
            if (MODE == 1 && nt >= 12) continue;
            short8 wf = *(const short8*)(&tab[b][(kk * 16 + nt) * 512 + l * 8]);
            acc[0][i] = __builtin_amdgcn_mfma_f32_16x16x32_bf16(wf, bf0, acc[0][i], 0, 0, 0);
            acc[1][i] = __builtin_amdgcn_mfma_f32_16x16x32_bf16(wf, bf1, acc[1][i], 0, 0, 0);
        }
    };

    float4 c0, c1, c2, c3, n0, n1, n2, n3;
    auto loadA = [&](int kc, float4& x0, float4& x1, float4& x2, float4& x3) {
        const float4* p0 = (const float4*)(arow0 + kc * 32);
        const float4* p1 = (const float4*)(arow1 + kc * 32);
        x0 = p0[0]; x1 = p0[1]; x2 = p1[0]; x3 = p1[1];
    };

    loadA(0, c0, c1, c2, c3);
    load_q(0, 0);
    __syncthreads();
    load_q(1, 1);

    loadA(1, n0, n1, n2, n3);  step(0, 0, c0, c1, c2, c3);
    loadA(2, c0, c1, c2, c3);  step(0, 1, n0, n1, n2, n3);
    __syncthreads();
    load_q(0, 2);
    loadA(3, n0, n1, n2, n3);  step(1, 0, c0, c1, c2, c3);
    loadA(4, c0, c1, c2, c3);  step(1, 1, n0, n1, n2, n3);
    __syncthreads();
    load_q(1, 3);
    loadA(5, n0, n1, n2, n3);  step(0, 0, c0, c1, c2, c3);
    loadA(6, c0, c1, c2, c3);  step(0, 1, n0, n1, n2, n3);
    __syncthreads();
    loadA(7, n0, n1, n2, n3);  step(1, 0, c0, c1, c2, c3);
                               step(1, 1, n0, n1, n2, n3);

    #pragma unroll
    for (int mg = 0; mg < 2; mg++) {
        int mRow = (mg == 0) ? mRow0 : mRow1;
        if (mRow >= M) continue;
        #pragma unroll
        for (int i = 0; i < 4; i++) {
            int nt = wn * 4 + i;
            if (MODE == 1 && nt >= 12) continue;
            int n0c = nt * 16 + lg * 4;
            float4 bv = *(const float4*)(bias + n0c);
            float v0 = acc[mg][i][0] + bv.x, v1 = acc[mg][i][1] + bv.y;
            float v2 = acc[mg][i][2] + bv.z, v3 = acc[mg][i][3] + bv.w;
            if (MODE == 1) {
                float4 o; o.x = v0; o.y = v1; o.z = v2; o.w = v3;
                *(float4*)((float*)out + (size_t)mRow * 192 + n0c) = o;
            } else {
                float4 rz = *(const float4*)(resid + (size_t)mRow * 256 + n0c);
                float4 o; o.x = v0 + rz.x; o.y = v1 + rz.y; o.z = v2 + rz.z; o.w = v3 + rz.w;
                *(float4*)((float*)out + (size_t)mRow * 256 + n0c) = o;
            }
        }
    }
}

__global__ __launch_bounds__(512)
void gemm_oa(const float* __restrict__ A, const short* __restrict__ Wtab,
             const float* __restrict__ bias, void* __restrict__ out, int M) {
    gemm_tab_body<1>(A, Wtab, bias, nullptr, out, M);
}
__global__ __launch_bounds__(512)
void gemm_out(const float* __restrict__ A, const short* __restrict__ Wtab,
              const float* __restrict__ bias, const float* __restrict__ resid,
              void* __restrict__ out, int M) {
    gemm_tab_body<2>(A, Wtab, bias, resid, out, M);
}

// ---------------- K4: fused softmax + bilinear sample + cam average ----------------
// NATURAL vproj layout. unit = 8 lanes per (q,h); lane sub reads bytes h*32+sub*4.
__global__ __launch_bounds__(256)
void sample_kernel(const unsigned char* __restrict__ vproj, const float* __restrict__ offattn,
                   const float* __restrict__ refp, const float* __restrict__ hit,
                   const float* __restrict__ invcnt, float* __restrict__ slots) {
    int bid = blockIdx.x;
    int xcd = bid & 7, idx = bid >> 3;
    const int qch = 312, rch = 4;
    int start = (xcd < rch) ? xcd * (qch + 1) : rch * (qch + 1) + (xcd - rch) * qch;
    int wg = start + idx;

    int row2 = wg / 50, col2 = wg % 50;

    int tid = threadIdx.x;
    int unit = tid >> 3;
    int sub = tid & 7;
    int qi = unit >> 3;
    int h = unit & 7;
    int q = (row2 * 2 + (qi >> 1)) * 100 + col2 * 2 + (qi & 1);

    const float* oa = offattn + (size_t)q * 192;
    float ox[8], oy[8], aw[8];
    float m = -1e30f;
    #pragma unroll
    for (int p = 0; p < 8; p++) {
        ox[p] = oa[h * 16 + 2 * p];
        oy[p] = oa[h * 16 + 2 * p + 1];
        float lg = oa[128 + h * 8 + p];
        aw[p] = lg;
        m = fmaxf(m, lg);
    }
    float s = 0.f;
    #pragma unroll
    for (int p = 0; p < 8; p++) { aw[p] = __expf(aw[p] - m); s += aw[p]; }
    float is = 1.f / s;
    #pragma unroll
    for (int p = 0; p < 8; p++) aw[p] *= is;

    float a0 = 0.f, a1 = 0.f, a2 = 0.f, a3 = 0.f;
    const unsigned char* vb = vproj + h * 32 + sub * 4;

    auto acc4 = [&](unsigned u, float w) {
#if __has_builtin(__builtin_amdgcn_cvt_pk_f32_fp8)
        floatx2 lo = __builtin_amdgcn_cvt_pk_f32_fp8((int)u, false);
        floatx2 hi = __builtin_amdgcn_cvt_pk_f32_fp8((int)u, true);
        a0 = fmaf(w, lo.x, a0); a1 = fmaf(w, lo.y, a1);
        a2 = fmaf(w, hi.x, a2); a3 = fmaf(w, hi.y, a3);
#else
        a0 = fmaf(w, e4m3f_manual(u & 255), a0);
        a1 = fmaf(w, e4m3f_manual((u >> 8) & 255), a1);
        a2 = fmaf(w, e4m3f_manual((u >> 16) & 255), a2);
        a3 = fmaf(w, e4m3f_manual(u >> 24), a3);
#endif
    };

    for (int c = 0; c < CAMS; c++) {
        if (hit[c * QN + q] == 0.f) continue;
        const float* rp = refp + (size_t)(c * QN + q) * 8;
        float rx[4], ry[4];
        #pragma unroll
        for (int d = 0; d < 4; d++) {
            rx[d] = rp[2 * d]     * (float)WW - 0.5f;
            ry[d] = rp[2 * d + 1] * (float)HH - 0.5f;
        }
        const unsigned char* vc = vb + (size_t)c * (NV * 256);
        #pragma unroll
        for (int p = 0; p < 8; p++) {
            float x = rx[p & 3] + ox[p];
            float y = ry[p & 3] + oy[p];
            float xf = floorf(x), yf = floorf(y);
            float fx = x - xf, fy = y - yf;
            int x0 = (int)xf, y0 = (int)yf;
            int xc0 = min(max(x0, 0), WW - 1), xc1 = min(max(x0 + 1, 0), WW - 1);
            int yc0 = min(max(y0, 0), HH - 1), yc1 = min(max(y0 + 1, 0), HH - 1);
            float vx0 = ((unsigned)x0 < (unsigned)WW) ? 1.f : 0.f;
            float vx1 = ((unsigned)(x0 + 1) < (unsigned)WW) ? 1.f : 0.f;
            float vy0 = ((unsigned)y0 < (unsigned)HH) ? 1.f : 0.f;
            float vy1 = ((unsigned)(y0 + 1) < (unsigned)HH) ? 1.f : 0.f;
            float wp = aw[p];
            float wx0 = (1.f - fx) * vx0 * wp, wx1 = fx * vx1 * wp;
            float wy0 = (1.f - fy) * vy0,      wy1 = fy * vy1;
            unsigned u00 = *(const unsigned*)(vc + (size_t)(yc0 * WW + xc0) * 256);
            unsigned u10 = *(const unsigned*)(vc + (size_t)(yc0 * WW + xc1) * 256);
            unsigned u01 = *(const unsigned*)(vc + (size_t)(yc1 * WW + xc0) * 256);
            unsigned u11 = *(const unsigned*)(vc + (size_t)(yc1 * WW + xc1) * 256);
            acc4(u00, wx0 * wy0);
            acc4(u10, wx1 * wy0);
            acc4(u01, wx0 * wy1);
            acc4(u11, wx1 * wy1);
        }
    }
    float ic = invcnt[q];
    float* sp = slots + (size_t)q * 256 + h * 32 + sub * 4;
    float4 o; o.x = a0 * ic; o.y = a1 * ic; o.z = a2 * ic; o.w = a3 * ic;
    *(float4*)sp = o;
}

extern "C" void kernel_launch(void* const* d_in, const int* in_sizes, int n_in,
                              void* d_out, int out_size, void* d_ws, size_t ws_size,
                              hipStream_t stream) {
    const float* query   = (const float*)d_in[0];
    const float* value   = (const float*)d_in[2];
    const float* refp    = (const float*)d_in[3];
    const void*  mask    = d_in[4];
    const float* w_value = (const float*)d_in[7];
    const float* b_value = (const float*)d_in[8];
    const float* w_off   = (const float*)d_in[9];
    const float* b_off   = (const float*)d_in[10];
    const float* w_attn  = (const float*)d_in[11];
    const float* b_attn  = (const float*)d_in[12];
    const float* w_out   = (const float*)d_in[13];
    const float* b_out   = (const float*)d_in[14];
    float* out = (float*)d_out;

    char* w = (char*)d_ws;
    size_t o = 0;
    auto carve = [&](size_t bytes) { size_t r = o; o = (o + bytes + 255) & ~(size_t)255; return r; };
    int*   flag    = (int*)  (w + carve(4));
    float* hitv    = (float*)(w + carve(sizeof(float) * CAMS * QN));
    float* invc    = (float*)(w + carve(sizeof(float) * QN));
    short* tv      = (short*)(w + carve(2 * 65536));
    short* toa     = (short*)(w + carve(2 * 65536));
    short* tout    = (short*)(w + carve(2 * 65536));
    float* biasOA  = (float*)(w + carve(sizeof(float) * 192));
    unsigned char* vproj = (unsigned char*)(w + carve((size_t)MROW * 256));
    float* offattn = (float*)(w + carve(sizeof(float) * QN * 192));
    float* slots   = (float*)(w + carve(sizeof(float) * QN * 256));

    detect_kernel<<<1, 256, 0, stream>>>((const unsigned char*)mask, flag);
    prep_kernel<<<769, 256, 0, stream>>>(w_value, w_off, w_attn, w_out, b_off, b_attn,
                                         tv, toa, tout, biasOA);
    hit_kernel<<<(QN + 255) / 256, 256, 0, stream>>>(mask, flag, hitv, invc);

    gemm_v<<<(MROW + 127) / 128, 1024, 0, stream>>>(value, tv, b_value, vproj, MROW);
    gemm_oa<<<(QN + 63) / 64, 512, 0, stream>>>(query, toa, biasOA, offattn, QN);

    sample_kernel<<<2500, 256, 0, stream>>>(
        vproj, offattn, refp, hitv, invc, slots);

    gemm_out<<<(QN + 63) / 64, 512, 0, stream>>>(slots, tout, b_out, query, out, QN);
}

// Round 16
// 207.566 us; speedup vs baseline: 1.2322x; 1.2322x over previous
//
#include <hip/hip_runtime.h>
#include <hip/hip_bf16.h>

// SpatialCrossAttention (BEVFormer SCA) fused pipeline for MI355X/gfx950.
//  K0 detect  : infer bev_mask storage layout (u8 / i32 / f32)
//  K1 hit     : hit[c][q], invcnt[q]
//  K2 prep    : bf16 W-fragment tables x8 REPLICAS (one per XCD L2) + bias
//  gemm_v/oa/out: operand-swapped MFMA GEMM, W-table quarter-staged in LDS;
//               each block stages replica blockIdx&7 -> no cross-XCD L2
//               hot-line contention (R15 diagnosis).
//  K4 sample  : fused softmax + bilinear gather (HW fp8 cvt) + cam-average.

__device__ __forceinline__ void gload_lds16(const void* g, void* l) {
    __builtin_amdgcn_global_load_lds(
        (const __attribute__((address_space(1))) unsigned*)g,
        (__attribute__((address_space(3))) unsigned*)l, 16, 0, 0);
}

typedef __attribute__((ext_vector_type(8))) short short8;
typedef __attribute__((ext_vector_type(4))) float f32x4;
typedef __attribute__((ext_vector_type(2))) float floatx2;

__device__ __forceinline__ short f2bf(float f) {
    union { float f; unsigned u; } c; c.f = f;
    unsigned u = c.u;
    unsigned r = (u + 0x7FFFu + ((u >> 16) & 1u)) >> 16;  // RNE
    return (short)r;
}

// ---- fp8 e4m3fn decode/encode: HW cvt on gfx950, manual fallback ----
__device__ __forceinline__ float e4m3f_manual(unsigned b) {
    unsigned s = (b & 0x80u) << 24;
    unsigned e = (b >> 3) & 15u;
    unsigned m = b & 7u;
    if (e) return __uint_as_float(s | ((e + 120u) << 23) | (m << 20));
    return __uint_as_float(s | __float_as_uint((float)m * 0x1p-9f));
}
__device__ __forceinline__ unsigned char f2e4m3_manual(float x) {
    unsigned u = __float_as_uint(x);
    unsigned s = (u >> 24) & 0x80u;
    float ax = fabsf(x);
    if (!(ax > 0x1p-10f)) return (unsigned char)s;
    if (ax >= 440.f) return (unsigned char)(s | 0x7Eu);
    unsigned au = u & 0x7FFFFFFFu;
    int e = (int)(au >> 23) - 127;
    if (e >= -6) {
        unsigned r = au + 0x7FFFFu + ((au >> 20) & 1u);
        e = (int)(r >> 23) - 127;
        unsigned m = (r >> 20) & 7u;
        if (e > 8) return (unsigned char)(s | 0x7Eu);
        return (unsigned char)(s | (unsigned)((e + 7) << 3) | m);
    } else {
        int m = (int)rintf(ax * 512.f);
        return (unsigned char)(s | (unsigned)m);
    }
}

static constexpr int QN   = 10000;
static constexpr int CAMS = 6;
static constexpr int NV   = 23200;   // 116*200
static constexpr int HH   = 116;
static constexpr int WW   = 200;
static constexpr int MROW = CAMS * NV;  // 139200
static constexpr int TABE = 65536;      // entries per table copy (128KB)

// ---------------- K0: mask layout detect (16KB scan) ----------------
__global__ void detect_kernel(const unsigned char* __restrict__ mask, int* __restrict__ flag) {
    __shared__ unsigned s12[256], s3[256];
    unsigned o12 = 0, o3 = 0;
    for (int i = threadIdx.x; i < 16384; i += 256) {
        unsigned char b = mask[i];
        int m = i & 3;
        if (m == 1 || m == 2) o12 |= b;
        else if (m == 3) o3 |= b;
    }
    s12[threadIdx.x] = o12; s3[threadIdx.x] = o3;
    __syncthreads();
    if (threadIdx.x == 0) {
        unsigned a = 0, b = 0;
        for (int i = 0; i < 256; i++) { a |= s12[i]; b |= s3[i]; }
        *flag = a ? 0 : (b ? 2 : 1);  // 0=u8, 1=i32, 2=f32
    }
}

// ---------------- K1: hit / invcount ----------------
__global__ void hit_kernel(const void* __restrict__ mask, const int* __restrict__ flag,
                           float* __restrict__ hit, float* __restrict__ invcnt) {
    int q = blockIdx.x * 256 + threadIdx.x;
    if (q >= QN) return;
    int f = *flag;
    int cnt = 0;
    for (int c = 0; c < CAMS; c++) {
        bool any = false;
        #pragma unroll
        for (int d = 0; d < 4; d++) {
            size_t i = (size_t)(c * QN + q) * 4 + d;
            bool b;
            if (f == 0)      b = ((const unsigned char*)mask)[i] != 0;
            else if (f == 1) b = ((const int*)mask)[i] != 0;
            else             b = ((const float*)mask)[i] != 0.f;
            any |= b;
        }
        hit[c * QN + q] = any ? 1.f : 0.f;
        cnt += any ? 1 : 0;
    }
    invcnt[q] = 1.f / (float)(cnt > 0 ? cnt : 1);
}

// ---------------- K2: weight fragment tables (x8 replicas) ----------------
// entry e = ((kc*16 + nt)*64 + lane)*8 + j ;  W[kc*32 + (lane>>4)*8 + j][nt*16 + (lane&15)]
__global__ void prep_kernel(const float* __restrict__ wv, const float* __restrict__ woff,
                            const float* __restrict__ wattn, const float* __restrict__ wout,
                            const float* __restrict__ boff, const float* __restrict__ battn,
                            short* __restrict__ tv, short* __restrict__ toa,
                            short* __restrict__ tout, float* __restrict__ biasOA) {
    int id = blockIdx.x * 256 + threadIdx.x;
    if (id < 3 * TABE) {
        int t = id >> 16;
        int e = id & 65535;
        int j = e & 7, l = (e >> 3) & 63, nt = (e >> 9) & 15, kc = e >> 13;
        int k = kc * 32 + ((l >> 4) << 3) + j;
        int col = nt * 16 + (l & 15);
        float v;
        if (t == 0)      v = wv[k * 256 + col];
        else if (t == 1) v = (col < 128) ? woff[k * 128 + col]
                               : (col < 192 ? wattn[k * 64 + (col - 128)] : 0.f);
        else             v = wout[k * 256 + col];
        short* dst = (t == 0) ? tv : (t == 1) ? toa : tout;
        short bv = f2bf(v);
        #pragma unroll
        for (int c = 0; c < 8; c++) dst[c * TABE + e] = bv;   // 8 XCD replicas
    } else {
        int i = id - 3 * TABE;
        if (i < 192) biasOA[i] = (i < 128) ? boff[i] : battn[i - 128];
    }
}

__device__ __forceinline__ short8 cvt8(float4 x0, float4 x1) {
    unsigned u0, u1, u2, u3;
    asm("v_cvt_pk_bf16_f32 %0, %1, %2" : "=v"(u0) : "v"(x0.x), "v"(x0.y));
    asm("v_cvt_pk_bf16_f32 %0, %1, %2" : "=v"(u1) : "v"(x0.z), "v"(x0.w));
    asm("v_cvt_pk_bf16_f32 %0, %1, %2" : "=v"(u2) : "v"(x1.x), "v"(x1.y));
    asm("v_cvt_pk_bf16_f32 %0, %1, %2" : "=v"(u3) : "v"(x1.z), "v"(x1.w));
    union { unsigned u[4]; short8 s8; } uu;
    uu.u[0] = u0; uu.u[1] = u1; uu.u[2] = u2; uu.u[3] = u3;
    return uu.s8;
}

// ---------------- GEMM body (R10 structure + replica staging) ----------------
// out[m][n] = sum_k A[m][k]*W[k][n] (+bias per mode)
// Block = 128 rows x 256 cols, 512 thr / 8 waves; wave wv owns rows (blk*8+wv)*16..+15.
// W table: this block's XCD replica (blockIdx&7), 4 quarters (2 kc) double-buffered
// in 2x32KB LDS, 4 barriers. A rows: direct float4 pairs, ping-pong 1 kc ahead.
// MODE 0: fp8 packed u32 scattered stores (R11-verified clean WRITE_SIZE);
// MODE 1: f32 192 cols; MODE 2: f32 + resid.
template <int MODE>
__device__ __forceinline__
void gemm_tab_body(const float* __restrict__ A, const short* __restrict__ Wtab,
                   const float* __restrict__ bias, const float* __restrict__ resid,
                   void* __restrict__ out, int M) {
    __shared__ short tab[2][16384];                 // 2 x 32KB
    const int tid = threadIdx.x;
    const int l  = tid & 63;
    const int wv = tid >> 6;
    const int lr = l & 15;
    const int lg = l >> 4;
    const int mBase = (blockIdx.x * 8 + wv) * 16;
    const int mRow = mBase + lr;
    const int m = min(mRow, M - 1);
    const char* wsrc = (const char*)Wtab + (size_t)(blockIdx.x & 7) * (TABE * 2);

    auto load_q = [&](int b, int q) {
        #pragma unroll
        for (int it = 0; it < 4; it++) {
            int linear = (it * 512 + tid) * 16;
            const char* src = wsrc + q * 32768 + linear;
            char* dst = (char*)&tab[b][0] + it * 8192 + (tid & 448) * 16;  // wave-uniform
            gload_lds16(src, dst);
        }
    };

    f32x4 acc[16] = {};
    const float* arow = A + (size_t)m * 256 + lg * 8;

    auto loadAkc = [&](int kc, float4& x0, float4& x1) {
        const float4* p = (const float4*)(arow + kc * 32);
        x0 = p[0]; x1 = p[1];
    };
    auto stepKC = [&](int b, int kk, float4 x0, float4 x1) {
        short8 bfrag = cvt8(x0, x1);
        #pragma unroll
        for (int nt = 0; nt < 16; nt++) {
            if (MODE == 1 && nt >= 12) continue;
            short8 wf = *(const short8*)(&tab[b][(kk * 16 + nt) * 512 + l * 8]);
            acc[nt] = __builtin_amdgcn_mfma_f32_16x16x32_bf16(wf, bfrag, acc[nt], 0, 0, 0);
        }
    };

    float4 a0, a1, b0, b1;
    loadAkc(0, a0, a1);
    load_q(0, 0);
    __syncthreads();                  // q0 visible
    load_q(1, 1);

    loadAkc(1, b0, b1);  stepKC(0, 0, a0, a1);   // kc0
    loadAkc(2, a0, a1);  stepKC(0, 1, b0, b1);   // kc1
    __syncthreads();                  // q1 visible, buf0 free
    load_q(0, 2);
    loadAkc(3, b0, b1);  stepKC(1, 0, a0, a1);   // kc2
    loadAkc(4, a0, a1);  stepKC(1, 1, b0, b1);   // kc3
    __syncthreads();                  // q2 visible, buf1 free
    load_q(1, 3);
    loadAkc(5, b0, b1);  stepKC(0, 0, a0, a1);   // kc4
    loadAkc(6, a0, a1);  stepKC(0, 1, b0, b1);   // kc5
    __syncthreads();                  // q3 visible
    loadAkc(7, b0, b1);  stepKC(1, 0, a0, a1);   // kc6
                         stepKC(1, 1, b0, b1);   // kc7

    if (mRow < M) {
        #pragma unroll
        for (int nt = 0; nt < 16; nt++) {
            if (MODE == 1 && nt >= 12) continue;
            int n0 = nt * 16 + lg * 4;
            float4 bv = *(const float4*)(bias + n0);
            float v0 = acc[nt][0] + bv.x, v1 = acc[nt][1] + bv.y;
            float v2 = acc[nt][2] + bv.z, v3 = acc[nt][3] + bv.w;
            if (MODE == 0) {
                unsigned pk;
#if __has_builtin(__builtin_amdgcn_cvt_pk_fp8_f32)
                pk = __builtin_amdgcn_cvt_pk_fp8_f32(v0, v1, 0, false);
                pk = __builtin_amdgcn_cvt_pk_fp8_f32(v2, v3, pk, true);
#else
                pk = (unsigned)f2e4m3_manual(v0) | ((unsigned)f2e4m3_manual(v1) << 8)
                   | ((unsigned)f2e4m3_manual(v2) << 16) | ((unsigned)f2e4m3_manual(v3) << 24);
#endif
                ((unsigned*)out)[(size_t)mRow * 64 + (n0 >> 2)] = pk;
            } else if (MODE == 1) {
                float4 o; o.x = v0; o.y = v1; o.z = v2; o.w = v3;
                *(float4*)((float*)out + (size_t)mRow * 192 + n0) = o;
            } else {
                float4 rz = *(const float4*)(resid + (size_t)mRow * 256 + n0);
                float4 o; o.x = v0 + rz.x; o.y = v1 + rz.y; o.z = v2 + rz.z; o.w = v3 + rz.w;
                *(float4*)((float*)out + (size_t)mRow * 256 + n0) = o;
            }
        }
    }
}

__global__ __launch_bounds__(512)
void gemm_v(const float* __restrict__ A, const short* __restrict__ Wtab,
            const float* __restrict__ bias, void* __restrict__ out, int M) {
    gemm_tab_body<0>(A, Wtab, bias, nullptr, out, M);
}
__global__ __launch_bounds__(512)
void gemm_oa(const float* __restrict__ A, const short* __restrict__ Wtab,
             const float* __restrict__ bias, void* __restrict__ out, int M) {
    gemm_tab_body<1>(A, Wtab, bias, nullptr, out, M);
}
__global__ __launch_bounds__(512)
void gemm_out(const float* __restrict__ A, const short* __restrict__ Wtab,
              const float* __restrict__ bias, const float* __restrict__ resid,
              void* __restrict__ out, int M) {
    gemm_tab_body<2>(A, Wtab, bias, resid, out, M);
}

// ---------------- K4: fused softmax + bilinear sample + cam average ----------------
// NATURAL vproj layout (measured 101us). unit = 8 lanes per (q,h).
__global__ __launch_bounds__(256)
void sample_kernel(const unsigned char* __restrict__ vproj, const float* __restrict__ offattn,
                   const float* __restrict__ refp, const float* __restrict__ hit,
                   const float* __restrict__ invcnt, float* __restrict__ slots) {
    int bid = blockIdx.x;
    int xcd = bid & 7, idx = bid >> 3;
    const int qch = 312, rch = 4;
    int start = (xcd < rch) ? xcd * (qch + 1) : rch * (qch + 1) + (xcd - rch) * qch;
    int wg = start + idx;

    int row2 = wg / 50, col2 = wg % 50;

    int tid = threadIdx.x;
    int unit = tid >> 3;
    int sub = tid & 7;
    int qi = unit >> 3;
    int h = unit & 7;
    int q = (row2 * 2 + (qi >> 1)) * 100 + col2 * 2 + (qi & 1);

    const float* oa = offattn + (size_t)q * 192;
    float ox[8], oy[8], aw[8];
    float m = -1e30f;
    #pragma unroll
    for (int p = 0; p < 8; p++) {
        ox[p] = oa[h * 16 + 2 * p];
        oy[p] = oa[h * 16 + 2 * p + 1];
        float lg = oa[128 + h * 8 + p];
        aw[p] = lg;
        m = fmaxf(m, lg);
    }
    float s = 0.f;
    #pragma unroll
    for (int p = 0; p < 8; p++) { aw[p] = __expf(aw[p] - m); s += aw[p]; }
    float is = 1.f / s;
    #pragma unroll
    for (int p = 0; p < 8; p++) aw[p] *= is;

    float a0 = 0.f, a1 = 0.f, a2 = 0.f, a3 = 0.f;
    const unsigned char* vb = vproj + h * 32 + sub * 4;

    auto acc4 = [&](unsigned u, float w) {
#if __has_builtin(__builtin_amdgcn_cvt_pk_f32_fp8)
        floatx2 lo = __builtin_amdgcn_cvt_pk_f32_fp8((int)u, false);
        floatx2 hi = __builtin_amdgcn_cvt_pk_f32_fp8((int)u, true);
        a0 = fmaf(w, lo.x, a0); a1 = fmaf(w, lo.y, a1);
        a2 = fmaf(w, hi.x, a2); a3 = fmaf(w, hi.y, a3);
#else
        a0 = fmaf(w, e4m3f_manual(u & 255), a0);
        a1 = fmaf(w, e4m3f_manual((u >> 8) & 255), a1);
        a2 = fmaf(w, e4m3f_manual((u >> 16) & 255), a2);
        a3 = fmaf(w, e4m3f_manual(u >> 24), a3);
#endif
    };

    for (int c = 0; c < CAMS; c++) {
        if (hit[c * QN + q] == 0.f) continue;
        const float* rp = refp + (size_t)(c * QN + q) * 8;
        float rx[4], ry[4];
        #pragma unroll
        for (int d = 0; d < 4; d++) {
            rx[d] = rp[2 * d]     * (float)WW - 0.5f;
            ry[d] = rp[2 * d + 1] * (float)HH - 0.5f;
        }
        const unsigned char* vc = vb + (size_t)c * (NV * 256);
        #pragma unroll
        for (int p = 0; p < 8; p++) {
            float x = rx[p & 3] + ox[p];
            float y = ry[p & 3] + oy[p];
            float xf = floorf(x), yf = floorf(y);
            float fx = x - xf, fy = y - yf;
            int x0 = (int)xf, y0 = (int)yf;
            int xc0 = min(max(x0, 0), WW - 1), xc1 = min(max(x0 + 1, 0), WW - 1);
            int yc0 = min(max(y0, 0), HH - 1), yc1 = min(max(y0 + 1, 0), HH - 1);
            float vx0 = ((unsigned)x0 < (unsigned)WW) ? 1.f : 0.f;
            float vx1 = ((unsigned)(x0 + 1) < (unsigned)WW) ? 1.f : 0.f;
            float vy0 = ((unsigned)y0 < (unsigned)HH) ? 1.f : 0.f;
            float vy1 = ((unsigned)(y0 + 1) < (unsigned)HH) ? 1.f : 0.f;
            float wp = aw[p];
            float wx0 = (1.f - fx) * vx0 * wp, wx1 = fx * vx1 * wp;
            float wy0 = (1.f - fy) * vy0,      wy1 = fy * vy1;
            unsigned u00 = *(const unsigned*)(vc + (size_t)(yc0 * WW + xc0) * 256);
            unsigned u10 = *(const unsigned*)(vc + (size_t)(yc0 * WW + xc1) * 256);
            unsigned u01 = *(const unsigned*)(vc + (size_t)(yc1 * WW + xc0) * 256);
            unsigned u11 = *(const unsigned*)(vc + (size_t)(yc1 * WW + xc1) * 256);
            acc4(u00, wx0 * wy0);
            acc4(u10, wx1 * wy0);
            acc4(u01, wx0 * wy1);
            acc4(u11, wx1 * wy1);
        }
    }
    float ic = invcnt[q];
    float* sp = slots + (size_t)q * 256 + h * 32 + sub * 4;
    float4 o; o.x = a0 * ic; o.y = a1 * ic; o.z = a2 * ic; o.w = a3 * ic;
    *(float4*)sp = o;
}

extern "C" void kernel_launch(void* const* d_in, const int* in_sizes, int n_in,
                              void* d_out, int out_size, void* d_ws, size_t ws_size,
                              hipStream_t stream) {
    const float* query   = (const float*)d_in[0];
    const float* value   = (const float*)d_in[2];
    const float* refp    = (const float*)d_in[3];
    const void*  mask    = d_in[4];
    const float* w_value = (const float*)d_in[7];
    const float* b_value = (const float*)d_in[8];
    const float* w_off   = (const float*)d_in[9];
    const float* b_off   = (const float*)d_in[10];
    const float* w_attn  = (const float*)d_in[11];
    const float* b_attn  = (const float*)d_in[12];
    const float* w_out   = (const float*)d_in[13];
    const float* b_out   = (const float*)d_in[14];
    float* out = (float*)d_out;

    char* w = (char*)d_ws;
    size_t o = 0;
    auto carve = [&](size_t bytes) { size_t r = o; o = (o + bytes + 255) & ~(size_t)255; return r; };
    int*   flag    = (int*)  (w + carve(4));
    float* hitv    = (float*)(w + carve(sizeof(float) * CAMS * QN));
    float* invc    = (float*)(w + carve(sizeof(float) * QN));
    short* tv      = (short*)(w + carve(2 * TABE * 8));
    short* toa     = (short*)(w + carve(2 * TABE * 8));
    short* tout    = (short*)(w + carve(2 * TABE * 8));
    float* biasOA  = (float*)(w + carve(sizeof(float) * 192));
    unsigned char* vproj = (unsigned char*)(w + carve((size_t)MROW * 256));
    float* offattn = (float*)(w + carve(sizeof(float) * QN * 192));
    float* slots   = (float*)(w + carve(sizeof(float) * QN * 256));

    detect_kernel<<<1, 256, 0, stream>>>((const unsigned char*)mask, flag);
    prep_kernel<<<769, 256, 0, stream>>>(w_value, w_off, w_attn, w_out, b_off, b_attn,
                                         tv, toa, tout, biasOA);
    hit_kernel<<<(QN + 255) / 256, 256, 0, stream>>>(mask, flag, hitv, invc);

    gemm_v<<<(MROW + 127) / 128, 512, 0, stream>>>(value, tv, b_value, vproj, MROW);
    gemm_oa<<<(QN + 127) / 128, 512, 0, stream>>>(query, toa, biasOA, offattn, QN);

    sample_kernel<<<2500, 256, 0, stream>>>(
        vproj, offattn, refp, hitv, invc, slots);

    gemm_out<<<(QN + 127) / 128, 512, 0, stream>>>(slots, tout, b_out, query, out, QN);
}

// Round 17
// 172.608 us; speedup vs baseline: 1.4817x; 1.2025x over previous
//
#include <hip/hip_runtime.h>
#include <hip/hip_bf16.h>

// SpatialCrossAttention (BEVFormer SCA) fused pipeline for MI355X/gfx950.
//  K0 detect  : infer bev_mask storage layout (u8 / i32 / f32)
//  K1 hit     : hit[c][q], invcnt[q]
//  K2 prep    : bf16 W-fragment tables x8 replicas (per-XCD L2) + bias
//  gemm_v/oa/out: operand-swapped MFMA GEMM, W-table quarter-staged in LDS,
//               per-XCD table replica (R16).
//  gemm_v out : HEAD-PLANAR fp8 vproj: plane[h][cam][pix][32B] (4.45MB/plane)
//  K4 sample  : head-pinned blocks (bid%8 == head == XCD) -> each XCD's
//               working set = one head plane ~= its 4MB L2 (R17 thesis).

__device__ __forceinline__ void gload_lds16(const void* g, void* l) {
    __builtin_amdgcn_global_load_lds(
        (const __attribute__((address_space(1))) unsigned*)g,
        (__attribute__((address_space(3))) unsigned*)l, 16, 0, 0);
}

typedef __attribute__((ext_vector_type(8))) short short8;
typedef __attribute__((ext_vector_type(4))) float f32x4;
typedef __attribute__((ext_vector_type(2))) float floatx2;

__device__ __forceinline__ short f2bf(float f) {
    union { float f; unsigned u; } c; c.f = f;
    unsigned u = c.u;
    unsigned r = (u + 0x7FFFu + ((u >> 16) & 1u)) >> 16;  // RNE
    return (short)r;
}

// ---- fp8 e4m3fn decode/encode: HW cvt on gfx950, manual fallback ----
__device__ __forceinline__ float e4m3f_manual(unsigned b) {
    unsigned s = (b & 0x80u) << 24;
    unsigned e = (b >> 3) & 15u;
    unsigned m = b & 7u;
    if (e) return __uint_as_float(s | ((e + 120u) << 23) | (m << 20));
    return __uint_as_float(s | __float_as_uint((float)m * 0x1p-9f));
}
__device__ __forceinline__ unsigned char f2e4m3_manual(float x) {
    unsigned u = __float_as_uint(x);
    unsigned s = (u >> 24) & 0x80u;
    float ax = fabsf(x);
    if (!(ax > 0x1p-10f)) return (unsigned char)s;
    if (ax >= 440.f) return (unsigned char)(s | 0x7Eu);
    unsigned au = u & 0x7FFFFFFFu;
    int e = (int)(au >> 23) - 127;
    if (e >= -6) {
        unsigned r = au + 0x7FFFFu + ((au >> 20) & 1u);
        e = (int)(r >> 23) - 127;
        unsigned m = (r >> 20) & 7u;
        if (e > 8) return (unsigned char)(s | 0x7Eu);
        return (unsigned char)(s | (unsigned)((e + 7) << 3) | m);
    } else {
        int m = (int)rintf(ax * 512.f);
        return (unsigned char)(s | (unsigned)m);
    }
}

static constexpr int QN   = 10000;
static constexpr int CAMS = 6;
static constexpr int NV   = 23200;   // 116*200
static constexpr int HH   = 116;
static constexpr int WW   = 200;
static constexpr int MROW = CAMS * NV;  // 139200
static constexpr int TABE = 65536;      // entries per table copy (128KB)

// ---------------- K0: mask layout detect (16KB scan) ----------------
__global__ void detect_kernel(const unsigned char* __restrict__ mask, int* __restrict__ flag) {
    __shared__ unsigned s12[256], s3[256];
    unsigned o12 = 0, o3 = 0;
    for (int i = threadIdx.x; i < 16384; i += 256) {
        unsigned char b = mask[i];
        int m = i & 3;
        if (m == 1 || m == 2) o12 |= b;
        else if (m == 3) o3 |= b;
    }
    s12[threadIdx.x] = o12; s3[threadIdx.x] = o3;
    __syncthreads();
    if (threadIdx.x == 0) {
        unsigned a = 0, b = 0;
        for (int i = 0; i < 256; i++) { a |= s12[i]; b |= s3[i]; }
        *flag = a ? 0 : (b ? 2 : 1);  // 0=u8, 1=i32, 2=f32
    }
}

// ---------------- K1: hit / invcount ----------------
__global__ void hit_kernel(const void* __restrict__ mask, const int* __restrict__ flag,
                           float* __restrict__ hit, float* __restrict__ invcnt) {
    int q = blockIdx.x * 256 + threadIdx.x;
    if (q >= QN) return;
    int f = *flag;
    int cnt = 0;
    for (int c = 0; c < CAMS; c++) {
        bool any = false;
        #pragma unroll
        for (int d = 0; d < 4; d++) {
            size_t i = (size_t)(c * QN + q) * 4 + d;
            bool b;
            if (f == 0)      b = ((const unsigned char*)mask)[i] != 0;
            else if (f == 1) b = ((const int*)mask)[i] != 0;
            else             b = ((const float*)mask)[i] != 0.f;
            any |= b;
        }
        hit[c * QN + q] = any ? 1.f : 0.f;
        cnt += any ? 1 : 0;
    }
    invcnt[q] = 1.f / (float)(cnt > 0 ? cnt : 1);
}

// ---------------- K2: weight fragment tables (x8 replicas) ----------------
// entry e = ((kc*16 + nt)*64 + lane)*8 + j ;  W[kc*32 + (lane>>4)*8 + j][nt*16 + (lane&15)]
__global__ void prep_kernel(const float* __restrict__ wv, const float* __restrict__ woff,
                            const float* __restrict__ wattn, const float* __restrict__ wout,
                            const float* __restrict__ boff, const float* __restrict__ battn,
                            short* __restrict__ tv, short* __restrict__ toa,
                            short* __restrict__ tout, float* __restrict__ biasOA) {
    int id = blockIdx.x * 256 + threadIdx.x;
    if (id < 3 * TABE) {
        int t = id >> 16;
        int e = id & 65535;
        int j = e & 7, l = (e >> 3) & 63, nt = (e >> 9) & 15, kc = e >> 13;
        int k = kc * 32 + ((l >> 4) << 3) + j;
        int col = nt * 16 + (l & 15);
        float v;
        if (t == 0)      v = wv[k * 256 + col];
        else if (t == 1) v = (col < 128) ? woff[k * 128 + col]
                               : (col < 192 ? wattn[k * 64 + (col - 128)] : 0.f);
        else             v = wout[k * 256 + col];
        short* dst = (t == 0) ? tv : (t == 1) ? toa : tout;
        short bv = f2bf(v);
        #pragma unroll
        for (int c = 0; c < 8; c++) dst[c * TABE + e] = bv;   // 8 XCD replicas
    } else {
        int i = id - 3 * TABE;
        if (i < 192) biasOA[i] = (i < 128) ? boff[i] : battn[i - 128];
    }
}

__device__ __forceinline__ short8 cvt8(float4 x0, float4 x1) {
    unsigned u0, u1, u2, u3;
    asm("v_cvt_pk_bf16_f32 %0, %1, %2" : "=v"(u0) : "v"(x0.x), "v"(x0.y));
    asm("v_cvt_pk_bf16_f32 %0, %1, %2" : "=v"(u1) : "v"(x0.z), "v"(x0.w));
    asm("v_cvt_pk_bf16_f32 %0, %1, %2" : "=v"(u2) : "v"(x1.x), "v"(x1.y));
    asm("v_cvt_pk_bf16_f32 %0, %1, %2" : "=v"(u3) : "v"(x1.z), "v"(x1.w));
    union { unsigned u[4]; short8 s8; } uu;
    uu.u[0] = u0; uu.u[1] = u1; uu.u[2] = u2; uu.u[3] = u3;
    return uu.s8;
}

// ---------------- GEMM body (R16 structure + replica staging) ----------------
// out[m][n] = sum_k A[m][k]*W[k][n] (+bias per mode)
// Block = 128 rows x 256 cols, 512 thr / 8 waves.
// MODE 0: fp8 u32 granules into HEAD-PLANAR vproj:
//         u32 index = (nt>>1)*MROW*8 + m*8 + (nt&1)*4 + lg
// MODE 1: f32 192 cols; MODE 2: f32 + resid.
template <int MODE>
__device__ __forceinline__
void gemm_tab_body(const float* __restrict__ A, const short* __restrict__ Wtab,
                   const float* __restrict__ bias, const float* __restrict__ resid,
                   void* __restrict__ out, int M) {
    __shared__ short tab[2][16384];                 // 2 x 32KB
    const int tid = threadIdx.x;
    const int l  = tid & 63;
    const int wv = tid >> 6;
    const int lr = l & 15;
    const int lg = l >> 4;
    const int mBase = (blockIdx.x * 8 + wv) * 16;
    const int mRow = mBase + lr;
    const int m = min(mRow, M - 1);
    const char* wsrc = (const char*)Wtab + (size_t)(blockIdx.x & 7) * (TABE * 2);

    auto load_q = [&](int b, int q) {
        #pragma unroll
        for (int it = 0; it < 4; it++) {
            int linear = (it * 512 + tid) * 16;
            const char* src = wsrc + q * 32768 + linear;
            char* dst = (char*)&tab[b][0] + it * 8192 + (tid & 448) * 16;  // wave-uniform
            gload_lds16(src, dst);
        }
    };

    f32x4 acc[16] = {};
    const float* arow = A + (size_t)m * 256 + lg * 8;

    auto loadAkc = [&](int kc, float4& x0, float4& x1) {
        const float4* p = (const float4*)(arow + kc * 32);
        x0 = p[0]; x1 = p[1];
    };
    auto stepKC = [&](int b, int kk, float4 x0, float4 x1) {
        short8 bfrag = cvt8(x0, x1);
        #pragma unroll
        for (int nt = 0; nt < 16; nt++) {
            if (MODE == 1 && nt >= 12) continue;
            short8 wf = *(const short8*)(&tab[b][(kk * 16 + nt) * 512 + l * 8]);
            acc[nt] = __builtin_amdgcn_mfma_f32_16x16x32_bf16(wf, bfrag, acc[nt], 0, 0, 0);
        }
    };

    float4 a0, a1, b0, b1;
    loadAkc(0, a0, a1);
    load_q(0, 0);
    __syncthreads();                  // q0 visible
    load_q(1, 1);

    loadAkc(1, b0, b1);  stepKC(0, 0, a0, a1);   // kc0
    loadAkc(2, a0, a1);  stepKC(0, 1, b0, b1);   // kc1
    __syncthreads();                  // q1 visible, buf0 free
    load_q(0, 2);
    loadAkc(3, b0, b1);  stepKC(1, 0, a0, a1);   // kc2
    loadAkc(4, a0, a1);  stepKC(1, 1, b0, b1);   // kc3
    __syncthreads();                  // q2 visible, buf1 free
    load_q(1, 3);
    loadAkc(5, b0, b1);  stepKC(0, 0, a0, a1);   // kc4
    loadAkc(6, a0, a1);  stepKC(0, 1, b0, b1);   // kc5
    __syncthreads();                  // q3 visible
    loadAkc(7, b0, b1);  stepKC(1, 0, a0, a1);   // kc6
                         stepKC(1, 1, b0, b1);   // kc7

    if (mRow < M) {
        #pragma unroll
        for (int nt = 0; nt < 16; nt++) {
            if (MODE == 1 && nt >= 12) continue;
            int n0 = nt * 16 + lg * 4;
            float4 bv = *(const float4*)(bias + n0);
            float v0 = acc[nt][0] + bv.x, v1 = acc[nt][1] + bv.y;
            float v2 = acc[nt][2] + bv.z, v3 = acc[nt][3] + bv.w;
            if (MODE == 0) {
                unsigned pk;
#if __has_builtin(__builtin_amdgcn_cvt_pk_fp8_f32)
                pk = __builtin_amdgcn_cvt_pk_fp8_f32(v0, v1, 0, false);
                pk = __builtin_amdgcn_cvt_pk_fp8_f32(v2, v3, pk, true);
#else
                pk = (unsigned)f2e4m3_manual(v0) | ((unsigned)f2e4m3_manual(v1) << 8)
                   | ((unsigned)f2e4m3_manual(v2) << 16) | ((unsigned)f2e4m3_manual(v3) << 24);
#endif
                // head-planar: plane nt>>1, slot (nt&1)*4+lg of row mRow
                ((unsigned*)out)[(size_t)(nt >> 1) * MROW * 8 + (size_t)mRow * 8
                                 + (nt & 1) * 4 + lg] = pk;
            } else if (MODE == 1) {
                float4 o; o.x = v0; o.y = v1; o.z = v2; o.w = v3;
                *(float4*)((float*)out + (size_t)mRow * 192 + n0) = o;
            } else {
                float4 rz = *(const float4*)(resid + (size_t)mRow * 256 + n0);
                float4 o; o.x = v0 + rz.x; o.y = v1 + rz.y; o.z = v2 + rz.z; o.w = v3 + rz.w;
                *(float4*)((float*)out + (size_t)mRow * 256 + n0) = o;
            }
        }
    }
}

__global__ __launch_bounds__(512)
void gemm_v(const float* __restrict__ A, const short* __restrict__ Wtab,
            const float* __restrict__ bias, void* __restrict__ out, int M) {
    gemm_tab_body<0>(A, Wtab, bias, nullptr, out, M);
}
__global__ __launch_bounds__(512)
void gemm_oa(const float* __restrict__ A, const short* __restrict__ Wtab,
             const float* __restrict__ bias, void* __restrict__ out, int M) {
    gemm_tab_body<1>(A, Wtab, bias, nullptr, out, M);
}
__global__ __launch_bounds__(512)
void gemm_out(const float* __restrict__ A, const short* __restrict__ Wtab,
              const float* __restrict__ bias, const float* __restrict__ resid,
              void* __restrict__ out, int M) {
    gemm_tab_body<2>(A, Wtab, bias, resid, out, M);
}

// ---------------- K4: head-pinned sampler (head == blockIdx%8 == XCD) -------
// Block: head h = bid&7, queries qbase=(bid>>3)*32 .. +31 (32 units x 8 lanes).
// vproj plane h: u32 index = h*MROW*8 + (cam*NV + pix)*8 + sub.
// Each XCD's working set ~= one 4.45MB head plane -> L2-resident.
__global__ __launch_bounds__(256)
void sample_kernel(const unsigned char* __restrict__ vproj, const float* __restrict__ offattn,
                   const float* __restrict__ refp, const float* __restrict__ hit,
                   const float* __restrict__ invcnt, float* __restrict__ slots) {
    int bid = blockIdx.x;
    int h = bid & 7;
    int qbase = (bid >> 3) * 32;

    int tid = threadIdx.x;
    int unit = tid >> 3;              // 0..31
    int sub = tid & 7;
    int q = qbase + unit;
    if (q >= QN) return;

    const float* oa = offattn + (size_t)q * 192;
    float ox[8], oy[8], aw[8];
    float m = -1e30f;
    #pragma unroll
    for (int p = 0; p < 8; p++) {
        ox[p] = oa[h * 16 + 2 * p];
        oy[p] = oa[h * 16 + 2 * p + 1];
        float lg = oa[128 + h * 8 + p];
        aw[p] = lg;
        m = fmaxf(m, lg);
    }
    float s = 0.f;
    #pragma unroll
    for (int p = 0; p < 8; p++) { aw[p] = __expf(aw[p] - m); s += aw[p]; }
    float is = 1.f / s;
    #pragma unroll
    for (int p = 0; p < 8; p++) aw[p] *= is;

    float a0 = 0.f, a1 = 0.f, a2 = 0.f, a3 = 0.f;
    const unsigned* plane = (const unsigned*)vproj + (size_t)h * MROW * 8 + sub;

    auto acc4 = [&](unsigned u, float w) {
#if __has_builtin(__builtin_amdgcn_cvt_pk_f32_fp8)
        floatx2 lo = __builtin_amdgcn_cvt_pk_f32_fp8((int)u, false);
        floatx2 hi = __builtin_amdgcn_cvt_pk_f32_fp8((int)u, true);
        a0 = fmaf(w, lo.x, a0); a1 = fmaf(w, lo.y, a1);
        a2 = fmaf(w, hi.x, a2); a3 = fmaf(w, hi.y, a3);
#else
        a0 = fmaf(w, e4m3f_manual(u & 255), a0);
        a1 = fmaf(w, e4m3f_manual((u >> 8) & 255), a1);
        a2 = fmaf(w, e4m3f_manual((u >> 16) & 255), a2);
        a3 = fmaf(w, e4m3f_manual(u >> 24), a3);
#endif
    };

    for (int c = 0; c < CAMS; c++) {
        if (hit[c * QN + q] == 0.f) continue;
        const float* rp = refp + (size_t)(c * QN + q) * 8;
        float rx[4], ry[4];
        #pragma unroll
        for (int d = 0; d < 4; d++) {
            rx[d] = rp[2 * d]     * (float)WW - 0.5f;
            ry[d] = rp[2 * d + 1] * (float)HH - 0.5f;
        }
        const unsigned* vc = plane + (size_t)c * NV * 8;
        #pragma unroll
        for (int p = 0; p < 8; p++) {
            float x = rx[p & 3] + ox[p];
            float y = ry[p & 3] + oy[p];
            float xf = floorf(x), yf = floorf(y);
            float fx = x - xf, fy = y - yf;
            int x0 = (int)xf, y0 = (int)yf;
            int xc0 = min(max(x0, 0), WW - 1), xc1 = min(max(x0 + 1, 0), WW - 1);
            int yc0 = min(max(y0, 0), HH - 1), yc1 = min(max(y0 + 1, 0), HH - 1);
            float vx0 = ((unsigned)x0 < (unsigned)WW) ? 1.f : 0.f;
            float vx1 = ((unsigned)(x0 + 1) < (unsigned)WW) ? 1.f : 0.f;
            float vy0 = ((unsigned)y0 < (unsigned)HH) ? 1.f : 0.f;
            float vy1 = ((unsigned)(y0 + 1) < (unsigned)HH) ? 1.f : 0.f;
            float wp = aw[p];
            float wx0 = (1.f - fx) * vx0 * wp, wx1 = fx * vx1 * wp;
            float wy0 = (1.f - fy) * vy0,      wy1 = fy * vy1;
            int b0 = yc0 * WW, b1 = yc1 * WW;
            unsigned u00 = vc[(size_t)(b0 + xc0) * 8];
            unsigned u10 = vc[(size_t)(b0 + xc1) * 8];
            unsigned u01 = vc[(size_t)(b1 + xc0) * 8];
            unsigned u11 = vc[(size_t)(b1 + xc1) * 8];
            acc4(u00, wx0 * wy0);
            acc4(u10, wx1 * wy0);
            acc4(u01, wx0 * wy1);
            acc4(u11, wx1 * wy1);
        }
    }
    float ic = invcnt[q];
    float* sp = slots + (size_t)q * 256 + h * 32 + sub * 4;
    float4 o; o.x = a0 * ic; o.y = a1 * ic; o.z = a2 * ic; o.w = a3 * ic;
    *(float4*)sp = o;
}

extern "C" void kernel_launch(void* const* d_in, const int* in_sizes, int n_in,
                              void* d_out, int out_size, void* d_ws, size_t ws_size,
                              hipStream_t stream) {
    const float* query   = (const float*)d_in[0];
    const float* value   = (const float*)d_in[2];
    const float* refp    = (const float*)d_in[3];
    const void*  mask    = d_in[4];
    const float* w_value = (const float*)d_in[7];
    const float* b_value = (const float*)d_in[8];
    const float* w_off   = (const float*)d_in[9];
    const float* b_off   = (const float*)d_in[10];
    const float* w_attn  = (const float*)d_in[11];
    const float* b_attn  = (const float*)d_in[12];
    const float* w_out   = (const float*)d_in[13];
    const float* b_out   = (const float*)d_in[14];
    float* out = (float*)d_out;

    char* w = (char*)d_ws;
    size_t o = 0;
    auto carve = [&](size_t bytes) { size_t r = o; o = (o + bytes + 255) & ~(size_t)255; return r; };
    int*   flag    = (int*)  (w + carve(4));
    float* hitv    = (float*)(w + carve(sizeof(float) * CAMS * QN));
    float* invc    = (float*)(w + carve(sizeof(float) * QN));
    short* tv      = (short*)(w + carve(2 * TABE * 8));
    short* toa     = (short*)(w + carve(2 * TABE * 8));
    short* tout    = (short*)(w + carve(2 * TABE * 8));
    float* biasOA  = (float*)(w + carve(sizeof(float) * 192));
    unsigned char* vproj = (unsigned char*)(w + carve((size_t)MROW * 256));
    float* offattn = (float*)(w + carve(sizeof(float) * QN * 192));
    float* slots   = (float*)(w + carve(sizeof(float) * QN * 256));

    detect_kernel<<<1, 256, 0, stream>>>((const unsigned char*)mask, flag);
    prep_kernel<<<769, 256, 0, stream>>>(w_value, w_off, w_attn, w_out, b_off, b_attn,
                                         tv, toa, tout, biasOA);
    hit_kernel<<<(QN + 255) / 256, 256, 0, stream>>>(mask, flag, hitv, invc);

    gemm_v<<<(MROW + 127) / 128, 512, 0, stream>>>(value, tv, b_value, vproj, MROW);
    gemm_oa<<<(QN + 127) / 128, 512, 0, stream>>>(query, toa, biasOA, offattn, QN);

    sample_kernel<<<2504, 256, 0, stream>>>(
        vproj, offattn, refp, hitv, invc, slots);

    gemm_out<<<(QN + 127) / 128, 512, 0, stream>>>(slots, tout, b_out, query, out, QN);
}

// Round 18
// 172.518 us; speedup vs baseline: 1.4825x; 1.0005x over previous
//
#include <hip/hip_runtime.h>
#include <hip/hip_bf16.h>

// SpatialCrossAttention (BEVFormer SCA) fused pipeline for MI355X/gfx950.
//  K0 detect  : infer bev_mask storage layout (u8 / i32 / f32)
//  K1 hit     : hit[c][q], invcnt[q]
//  K2 prep    : FP8 W_v fragment table (64KB) + bf16 tables for oa/out,
//               all x8 replicas (per-XCD L2) + bias
//  gemm_v     : fp8 MFMA GEMM, ENTIRE table in 64KB LDS, staged once,
//               ZERO mid-loop barriers (R18). Head-planar fp8 vproj out.
//  gemm_oa/out: bf16 quarter-staged LDS body (R16).
//  K4 sample  : head-pinned blocks (bid%8 == head == XCD), plane-per-L2.

__device__ __forceinline__ void gload_lds16(const void* g, void* l) {
    __builtin_amdgcn_global_load_lds(
        (const __attribute__((address_space(1))) unsigned*)g,
        (__attribute__((address_space(3))) unsigned*)l, 16, 0, 0);
}

typedef __attribute__((ext_vector_type(8))) short short8;
typedef __attribute__((ext_vector_type(4))) float f32x4;
typedef __attribute__((ext_vector_type(2))) float floatx2;

__device__ __forceinline__ short f2bf(float f) {
    union { float f; unsigned u; } c; c.f = f;
    unsigned u = c.u;
    unsigned r = (u + 0x7FFFu + ((u >> 16) & 1u)) >> 16;  // RNE
    return (short)r;
}

// ---- fp8 e4m3fn decode/encode: HW cvt on gfx950, manual fallback ----
__device__ __forceinline__ float e4m3f_manual(unsigned b) {
    unsigned s = (b & 0x80u) << 24;
    unsigned e = (b >> 3) & 15u;
    unsigned m = b & 7u;
    if (e) return __uint_as_float(s | ((e + 120u) << 23) | (m << 20));
    return __uint_as_float(s | __float_as_uint((float)m * 0x1p-9f));
}
__device__ __forceinline__ unsigned char f2e4m3_manual(float x) {
    unsigned u = __float_as_uint(x);
    unsigned s = (u >> 24) & 0x80u;
    float ax = fabsf(x);
    if (!(ax > 0x1p-10f)) return (unsigned char)s;
    if (ax >= 440.f) return (unsigned char)(s | 0x7Eu);
    unsigned au = u & 0x7FFFFFFFu;
    int e = (int)(au >> 23) - 127;
    if (e >= -6) {
        unsigned r = au + 0x7FFFFu + ((au >> 20) & 1u);
        e = (int)(r >> 23) - 127;
        unsigned m = (r >> 20) & 7u;
        if (e > 8) return (unsigned char)(s | 0x7Eu);
        return (unsigned char)(s | (unsigned)((e + 7) << 3) | m);
    } else {
        int m = (int)rintf(ax * 512.f);
        return (unsigned char)(s | (unsigned)m);
    }
}
__device__ __forceinline__ unsigned char enc_fp8(float v) {
#if __has_builtin(__builtin_amdgcn_cvt_pk_fp8_f32)
    return (unsigned char)(__builtin_amdgcn_cvt_pk_fp8_f32(v, v, 0, false) & 0xFF);
#else
    return f2e4m3_manual(v);
#endif
}

static constexpr int QN   = 10000;
static constexpr int CAMS = 6;
static constexpr int NV   = 23200;   // 116*200
static constexpr int HH   = 116;
static constexpr int WW   = 200;
static constexpr int MROW = CAMS * NV;  // 139200
static constexpr int TABE = 65536;      // entries per table copy

// ---------------- K0: mask layout detect (16KB scan) ----------------
__global__ void detect_kernel(const unsigned char* __restrict__ mask, int* __restrict__ flag) {
    __shared__ unsigned s12[256], s3[256];
    unsigned o12 = 0, o3 = 0;
    for (int i = threadIdx.x; i < 16384; i += 256) {
        unsigned char b = mask[i];
        int m = i & 3;
        if (m == 1 || m == 2) o12 |= b;
        else if (m == 3) o3 |= b;
    }
    s12[threadIdx.x] = o12; s3[threadIdx.x] = o3;
    __syncthreads();
    if (threadIdx.x == 0) {
        unsigned a = 0, b = 0;
        for (int i = 0; i < 256; i++) { a |= s12[i]; b |= s3[i]; }
        *flag = a ? 0 : (b ? 2 : 1);  // 0=u8, 1=i32, 2=f32
    }
}

// ---------------- K1: hit / invcount ----------------
__global__ void hit_kernel(const void* __restrict__ mask, const int* __restrict__ flag,
                           float* __restrict__ hit, float* __restrict__ invcnt) {
    int q = blockIdx.x * 256 + threadIdx.x;
    if (q >= QN) return;
    int f = *flag;
    int cnt = 0;
    for (int c = 0; c < CAMS; c++) {
        bool any = false;
        #pragma unroll
        for (int d = 0; d < 4; d++) {
            size_t i = (size_t)(c * QN + q) * 4 + d;
            bool b;
            if (f == 0)      b = ((const unsigned char*)mask)[i] != 0;
            else if (f == 1) b = ((const int*)mask)[i] != 0;
            else             b = ((const float*)mask)[i] != 0.f;
            any |= b;
        }
        hit[c * QN + q] = any ? 1.f : 0.f;
        cnt += any ? 1 : 0;
    }
    invcnt[q] = 1.f / (float)(cnt > 0 ? cnt : 1);
}

// ---------------- K2: weight fragment tables ----------------
// entry e = ((kc*16 + nt)*64 + lane)*8 + j ;  W[kc*32 + (lane>>4)*8 + j][nt*16 + (lane&15)]
// t==0: W_v as FP8 bytes (x8 replicas); t==1/2: oa/out as bf16 (x8 replicas).
__global__ void prep_kernel(const float* __restrict__ wv, const float* __restrict__ woff,
                            const float* __restrict__ wattn, const float* __restrict__ wout,
                            const float* __restrict__ boff, const float* __restrict__ battn,
                            unsigned char* __restrict__ tv8, short* __restrict__ toa,
                            short* __restrict__ tout, float* __restrict__ biasOA) {
    int id = blockIdx.x * 256 + threadIdx.x;
    if (id < 3 * TABE) {
        int t = id >> 16;
        int e = id & 65535;
        int j = e & 7, l = (e >> 3) & 63, nt = (e >> 9) & 15, kc = e >> 13;
        int k = kc * 32 + ((l >> 4) << 3) + j;
        int col = nt * 16 + (l & 15);
        if (t == 0) {
            unsigned char b = enc_fp8(wv[k * 256 + col]);
            #pragma unroll
            for (int c = 0; c < 8; c++) tv8[c * TABE + e] = b;
        } else {
            float v;
            if (t == 1) v = (col < 128) ? woff[k * 128 + col]
                              : (col < 192 ? wattn[k * 64 + (col - 128)] : 0.f);
            else        v = wout[k * 256 + col];
            short* dst = (t == 1) ? toa : tout;
            short bv = f2bf(v);
            #pragma unroll
            for (int c = 0; c < 8; c++) dst[c * TABE + e] = bv;
        }
    } else {
        int i = id - 3 * TABE;
        if (i < 192) biasOA[i] = (i < 128) ? boff[i] : battn[i - 128];
    }
}

__device__ __forceinline__ short8 cvt8(float4 x0, float4 x1) {
    unsigned u0, u1, u2, u3;
    asm("v_cvt_pk_bf16_f32 %0, %1, %2" : "=v"(u0) : "v"(x0.x), "v"(x0.y));
    asm("v_cvt_pk_bf16_f32 %0, %1, %2" : "=v"(u1) : "v"(x0.z), "v"(x0.w));
    asm("v_cvt_pk_bf16_f32 %0, %1, %2" : "=v"(u2) : "v"(x1.x), "v"(x1.y));
    asm("v_cvt_pk_bf16_f32 %0, %1, %2" : "=v"(u3) : "v"(x1.z), "v"(x1.w));
    union { unsigned u[4]; short8 s8; } uu;
    uu.u[0] = u0; uu.u[1] = u1; uu.u[2] = u2; uu.u[3] = u3;
    return uu.s8;
}

__device__ __forceinline__ long long pk8fp8(float4 x0, float4 x1) {
#if __has_builtin(__builtin_amdgcn_cvt_pk_fp8_f32)
    unsigned lo = (unsigned)__builtin_amdgcn_cvt_pk_fp8_f32(x0.x, x0.y, 0, false);
    lo = (unsigned)__builtin_amdgcn_cvt_pk_fp8_f32(x0.z, x0.w, (int)lo, true);
    unsigned hi = (unsigned)__builtin_amdgcn_cvt_pk_fp8_f32(x1.x, x1.y, 0, false);
    hi = (unsigned)__builtin_amdgcn_cvt_pk_fp8_f32(x1.z, x1.w, (int)hi, true);
#else
    unsigned lo = (unsigned)f2e4m3_manual(x0.x) | ((unsigned)f2e4m3_manual(x0.y) << 8)
                | ((unsigned)f2e4m3_manual(x0.z) << 16) | ((unsigned)f2e4m3_manual(x0.w) << 24);
    unsigned hi = (unsigned)f2e4m3_manual(x1.x) | ((unsigned)f2e4m3_manual(x1.y) << 8)
                | ((unsigned)f2e4m3_manual(x1.z) << 16) | ((unsigned)f2e4m3_manual(x1.w) << 24);
#endif
    return (long long)(((unsigned long long)hi << 32) | lo);
}

// ---------------- gemm_v: fp8 MFMA, whole table in LDS, barrier-free loop ------
// out[m][n] = sum_k A[m][k]*W[k][n] + bias -> fp8 head-planar vproj.
// Block = 128 rows x 256 cols, 512 thr / 8 waves; wave owns 16 rows x 256 cols.
// LDS = full 64KB fp8 table (replica blockIdx&7), staged once, ONE barrier.
// Per kc: pack A row (8 f32 -> 8 fp8), 16x ds_read_b64 + 16x mfma fp8.
__global__ __launch_bounds__(512)
void gemm_v(const float* __restrict__ A, const unsigned char* __restrict__ Wtab8,
            const float* __restrict__ bias, void* __restrict__ out, int M) {
    __shared__ unsigned char tab[65536];            // full fp8 table
    const int tid = threadIdx.x;
    const int l  = tid & 63;
    const int wv = tid >> 6;
    const int lr = l & 15;
    const int lg = l >> 4;
    const int mBase = (blockIdx.x * 8 + wv) * 16;
    const int mRow = mBase + lr;
    const int m = min(mRow, M - 1);
    const unsigned char* wsrc = Wtab8 + (size_t)(blockIdx.x & 7) * TABE;

    // stage full 64KB: 8 iters x 512 thr x 16B
    #pragma unroll
    for (int it = 0; it < 8; it++) {
        gload_lds16(wsrc + (it * 512 + tid) * 16,
                    (char*)tab + it * 8192 + (tid & 448) * 16);   // wave-uniform dst
    }

    const float* arow = A + (size_t)m * 256 + lg * 8;
    f32x4 acc[16] = {};

    float4 a0, a1, b0, b1;
    const float4* p0 = (const float4*)(arow);
    a0 = p0[0]; a1 = p0[1];
    __syncthreads();                                // table visible; ONLY barrier

    auto stepKC = [&](int kc, float4 x0, float4 x1) {
        long long bfrag = pk8fp8(x0, x1);
        #pragma unroll
        for (int nt = 0; nt < 16; nt++) {
            long long wf = *(const long long*)(&tab[(kc * 16 + nt) * 512 + l * 8]);
            acc[nt] = __builtin_amdgcn_mfma_f32_16x16x32_fp8_fp8(wf, bfrag, acc[nt], 0, 0, 0);
        }
    };

    #pragma unroll
    for (int kc = 0; kc < 8; kc += 2) {
        if (kc + 1 < 8) { const float4* p = (const float4*)(arow + (kc + 1) * 32); b0 = p[0]; b1 = p[1]; }
        stepKC(kc, a0, a1);
        if (kc + 2 < 8) { const float4* p = (const float4*)(arow + (kc + 2) * 32); a0 = p[0]; a1 = p[1]; }
        stepKC(kc + 1, b0, b1);
    }

    if (mRow < M) {
        #pragma unroll
        for (int nt = 0; nt < 16; nt++) {
            int n0 = nt * 16 + lg * 4;
            float4 bv = *(const float4*)(bias + n0);
            float v0 = acc[nt][0] + bv.x, v1 = acc[nt][1] + bv.y;
            float v2 = acc[nt][2] + bv.z, v3 = acc[nt][3] + bv.w;
            unsigned pk;
#if __has_builtin(__builtin_amdgcn_cvt_pk_fp8_f32)
            pk = __builtin_amdgcn_cvt_pk_fp8_f32(v0, v1, 0, false);
            pk = __builtin_amdgcn_cvt_pk_fp8_f32(v2, v3, pk, true);
#else
            pk = (unsigned)f2e4m3_manual(v0) | ((unsigned)f2e4m3_manual(v1) << 8)
               | ((unsigned)f2e4m3_manual(v2) << 16) | ((unsigned)f2e4m3_manual(v3) << 24);
#endif
            // head-planar: plane nt>>1, slot (nt&1)*4+lg of row mRow
            ((unsigned*)out)[(size_t)(nt >> 1) * MROW * 8 + (size_t)mRow * 8
                             + (nt & 1) * 4 + lg] = pk;
        }
    }
}

// ---------------- small-GEMM body (bf16, quarter-staged, R16) ----------------
template <int MODE>
__device__ __forceinline__
void gemm_tab_body(const float* __restrict__ A, const short* __restrict__ Wtab,
                   const float* __restrict__ bias, const float* __restrict__ resid,
                   void* __restrict__ out, int M) {
    __shared__ short tab[2][16384];                 // 2 x 32KB
    const int tid = threadIdx.x;
    const int l  = tid & 63;
    const int wv = tid >> 6;
    const int lr = l & 15;
    const int lg = l >> 4;
    const int mBase = (blockIdx.x * 8 + wv) * 16;
    const int mRow = mBase + lr;
    const int m = min(mRow, M - 1);
    const char* wsrc = (const char*)Wtab + (size_t)(blockIdx.x & 7) * (TABE * 2);

    auto load_q = [&](int b, int q) {
        #pragma unroll
        for (int it = 0; it < 4; it++) {
            int linear = (it * 512 + tid) * 16;
            const char* src = wsrc + q * 32768 + linear;
            char* dst = (char*)&tab[b][0] + it * 8192 + (tid & 448) * 16;
            gload_lds16(src, dst);
        }
    };

    f32x4 acc[16] = {};
    const float* arow = A + (size_t)m * 256 + lg * 8;

    auto loadAkc = [&](int kc, float4& x0, float4& x1) {
        const float4* p = (const float4*)(arow + kc * 32);
        x0 = p[0]; x1 = p[1];
    };
    auto stepKC = [&](int b, int kk, float4 x0, float4 x1) {
        short8 bfrag = cvt8(x0, x1);
        #pragma unroll
        for (int nt = 0; nt < 16; nt++) {
            if (MODE == 1 && nt >= 12) continue;
            short8 wf = *(const short8*)(&tab[b][(kk * 16 + nt) * 512 + l * 8]);
            acc[nt] = __builtin_amdgcn_mfma_f32_16x16x32_bf16(wf, bfrag, acc[nt], 0, 0, 0);
        }
    };

    float4 a0, a1, b0, b1;
    loadAkc(0, a0, a1);
    load_q(0, 0);
    __syncthreads();
    load_q(1, 1);

    loadAkc(1, b0, b1);  stepKC(0, 0, a0, a1);
    loadAkc(2, a0, a1);  stepKC(0, 1, b0, b1);
    __syncthreads();
    load_q(0, 2);
    loadAkc(3, b0, b1);  stepKC(1, 0, a0, a1);
    loadAkc(4, a0, a1);  stepKC(1, 1, b0, b1);
    __syncthreads();
    load_q(1, 3);
    loadAkc(5, b0, b1);  stepKC(0, 0, a0, a1);
    loadAkc(6, a0, a1);  stepKC(0, 1, b0, b1);
    __syncthreads();
    loadAkc(7, b0, b1);  stepKC(1, 0, a0, a1);
                         stepKC(1, 1, b0, b1);

    if (mRow < M) {
        #pragma unroll
        for (int nt = 0; nt < 16; nt++) {
            if (MODE == 1 && nt >= 12) continue;
            int n0 = nt * 16 + lg * 4;
            float4 bv = *(const float4*)(bias + n0);
            float v0 = acc[nt][0] + bv.x, v1 = acc[nt][1] + bv.y;
            float v2 = acc[nt][2] + bv.z, v3 = acc[nt][3] + bv.w;
            if (MODE == 1) {
                float4 o; o.x = v0; o.y = v1; o.z = v2; o.w = v3;
                *(float4*)((float*)out + (size_t)mRow * 192 + n0) = o;
            } else {
                float4 rz = *(const float4*)(resid + (size_t)mRow * 256 + n0);
                float4 o; o.x = v0 + rz.x; o.y = v1 + rz.y; o.z = v2 + rz.z; o.w = v3 + rz.w;
                *(float4*)((float*)out + (size_t)mRow * 256 + n0) = o;
            }
        }
    }
}

__global__ __launch_bounds__(512)
void gemm_oa(const float* __restrict__ A, const short* __restrict__ Wtab,
             const float* __restrict__ bias, void* __restrict__ out, int M) {
    gemm_tab_body<1>(A, Wtab, bias, nullptr, out, M);
}
__global__ __launch_bounds__(512)
void gemm_out(const float* __restrict__ A, const short* __restrict__ Wtab,
              const float* __restrict__ bias, const float* __restrict__ resid,
              void* __restrict__ out, int M) {
    gemm_tab_body<2>(A, Wtab, bias, resid, out, M);
}

// ---------------- K4: head-pinned sampler (head == blockIdx%8 == XCD) -------
__global__ __launch_bounds__(256)
void sample_kernel(const unsigned char* __restrict__ vproj, const float* __restrict__ offattn,
                   const float* __restrict__ refp, const float* __restrict__ hit,
                   const float* __restrict__ invcnt, float* __restrict__ slots) {
    int bid = blockIdx.x;
    int h = bid & 7;
    int qbase = (bid >> 3) * 32;

    int tid = threadIdx.x;
    int unit = tid >> 3;              // 0..31
    int sub = tid & 7;
    int q = qbase + unit;
    if (q >= QN) return;

    const float* oa = offattn + (size_t)q * 192;
    float ox[8], oy[8], aw[8];
    float m = -1e30f;
    #pragma unroll
    for (int p = 0; p < 8; p++) {
        ox[p] = oa[h * 16 + 2 * p];
        oy[p] = oa[h * 16 + 2 * p + 1];
        float lg = oa[128 + h * 8 + p];
        aw[p] = lg;
        m = fmaxf(m, lg);
    }
    float s = 0.f;
    #pragma unroll
    for (int p = 0; p < 8; p++) { aw[p] = __expf(aw[p] - m); s += aw[p]; }
    float is = 1.f / s;
    #pragma unroll
    for (int p = 0; p < 8; p++) aw[p] *= is;

    float a0 = 0.f, a1 = 0.f, a2 = 0.f, a3 = 0.f;
    const unsigned* plane = (const unsigned*)vproj + (size_t)h * MROW * 8 + sub;

    auto acc4 = [&](unsigned u, float w) {
#if __has_builtin(__builtin_amdgcn_cvt_pk_f32_fp8)
        floatx2 lo = __builtin_amdgcn_cvt_pk_f32_fp8((int)u, false);
        floatx2 hi = __builtin_amdgcn_cvt_pk_f32_fp8((int)u, true);
        a0 = fmaf(w, lo.x, a0); a1 = fmaf(w, lo.y, a1);
        a2 = fmaf(w, hi.x, a2); a3 = fmaf(w, hi.y, a3);
#else
        a0 = fmaf(w, e4m3f_manual(u & 255), a0);
        a1 = fmaf(w, e4m3f_manual((u >> 8) & 255), a1);
        a2 = fmaf(w, e4m3f_manual((u >> 16) & 255), a2);
        a3 = fmaf(w, e4m3f_manual(u >> 24), a3);
#endif
    };

    for (int c = 0; c < CAMS; c++) {
        if (hit[c * QN + q] == 0.f) continue;
        const float* rp = refp + (size_t)(c * QN + q) * 8;
        float rx[4], ry[4];
        #pragma unroll
        for (int d = 0; d < 4; d++) {
            rx[d] = rp[2 * d]     * (float)WW - 0.5f;
            ry[d] = rp[2 * d + 1] * (float)HH - 0.5f;
        }
        const unsigned* vc = plane + (size_t)c * NV * 8;
        #pragma unroll
        for (int p = 0; p < 8; p++) {
            float x = rx[p & 3] + ox[p];
            float y = ry[p & 3] + oy[p];
            float xf = floorf(x), yf = floorf(y);
            float fx = x - xf, fy = y - yf;
            int x0 = (int)xf, y0 = (int)yf;
            int xc0 = min(max(x0, 0), WW - 1), xc1 = min(max(x0 + 1, 0), WW - 1);
            int yc0 = min(max(y0, 0), HH - 1), yc1 = min(max(y0 + 1, 0), HH - 1);
            float vx0 = ((unsigned)x0 < (unsigned)WW) ? 1.f : 0.f;
            float vx1 = ((unsigned)(x0 + 1) < (unsigned)WW) ? 1.f : 0.f;
            float vy0 = ((unsigned)y0 < (unsigned)HH) ? 1.f : 0.f;
            float vy1 = ((unsigned)(y0 + 1) < (unsigned)HH) ? 1.f : 0.f;
            float wp = aw[p];
            float wx0 = (1.f - fx) * vx0 * wp, wx1 = fx * vx1 * wp;
            float wy0 = (1.f - fy) * vy0,      wy1 = fy * vy1;
            int b0 = yc0 * WW, b1 = yc1 * WW;
            unsigned u00 = vc[(size_t)(b0 + xc0) * 8];
            unsigned u10 = vc[(size_t)(b0 + xc1) * 8];
            unsigned u01 = vc[(size_t)(b1 + xc0) * 8];
            unsigned u11 = vc[(size_t)(b1 + xc1) * 8];
            acc4(u00, wx0 * wy0);
            acc4(u10, wx1 * wy0);
            acc4(u01, wx0 * wy1);
            acc4(u11, wx1 * wy1);
        }
    }
    float ic = invcnt[q];
    float* sp = slots + (size_t)q * 256 + h * 32 + sub * 4;
    float4 o; o.x = a0 * ic; o.y = a1 * ic; o.z = a2 * ic; o.w = a3 * ic;
    *(float4*)sp = o;
}

extern "C" void kernel_launch(void* const* d_in, const int* in_sizes, int n_in,
                              void* d_out, int out_size, void* d_ws, size_t ws_size,
                              hipStream_t stream) {
    const float* query   = (const float*)d_in[0];
    const float* value   = (const float*)d_in[2];
    const float* refp    = (const float*)d_in[3];
    const void*  mask    = d_in[4];
    const float* w_value = (const float*)d_in[7];
    const float* b_value = (const float*)d_in[8];
    const float* w_off   = (const float*)d_in[9];
    const float* b_off   = (const float*)d_in[10];
    const float* w_attn  = (const float*)d_in[11];
    const float* b_attn  = (const float*)d_in[12];
    const float* w_out   = (const float*)d_in[13];
    const float* b_out   = (const float*)d_in[14];
    float* out = (float*)d_out;

    char* w = (char*)d_ws;
    size_t o = 0;
    auto carve = [&](size_t bytes) { size_t r = o; o = (o + bytes + 255) & ~(size_t)255; return r; };
    int*   flag    = (int*)  (w + carve(4));
    float* hitv    = (float*)(w + carve(sizeof(float) * CAMS * QN));
    float* invc    = (float*)(w + carve(sizeof(float) * QN));
    unsigned char* tv8 = (unsigned char*)(w + carve((size_t)TABE * 8));
    short* toa     = (short*)(w + carve(2 * TABE * 8));
    short* tout    = (short*)(w + carve(2 * TABE * 8));
    float* biasOA  = (float*)(w + carve(sizeof(float) * 192));
    unsigned char* vproj = (unsigned char*)(w + carve((size_t)MROW * 256));
    float* offattn = (float*)(w + carve(sizeof(float) * QN * 192));
    float* slots   = (float*)(w + carve(sizeof(float) * QN * 256));

    detect_kernel<<<1, 256, 0, stream>>>((const unsigned char*)mask, flag);
    prep_kernel<<<769, 256, 0, stream>>>(w_value, w_off, w_attn, w_out, b_off, b_attn,
                                         tv8, toa, tout, biasOA);
    hit_kernel<<<(QN + 255) / 256, 256, 0, stream>>>(mask, flag, hitv, invc);

    gemm_v<<<(MROW + 127) / 128, 512, 0, stream>>>(value, tv8, b_value, vproj, MROW);
    gemm_oa<<<(QN + 127) / 128, 512, 0, stream>>>(query, toa, biasOA, offattn, QN);

    sample_kernel<<<2504, 256, 0, stream>>>(
        vproj, offattn, refp, hitv, invc, slots);

    gemm_out<<<(QN + 127) / 128, 512, 0, stream>>>(slots, tout, b_out, query, out, QN);
}